// Round 17
// baseline (39.133 us; speedup 1.0000x reference)
//
#include <hip/hip_runtime.h>

// QRNN fused kernel for MI355X.
// B=64, S=2048, VOCAB=128, HIDDEN=256, gates=768, emb=124, num=7.
//
// Ledger after r16 (total 32.9us): scan ~21 (VALU-issue-bound @ ~1GHz effective),
// precompute ~3, combine ~1.5, graph/launch gaps ~7.
// r16 lesson: trans ops = 1 issue slot (execution pipelined behind other waves);
// r15->r16 delta (-3%) matched slot count 29->26, not the trans-cycle model.
// r17: (1) OCCUPANCY -- scan grid was 512 blocks = 2 blocks/CU = 16 waves/CU
// (half the chip's wave slots; r14's 76% VALUBusy was at 8 waves/SIMD, current
// runs 4). CHUNKS 32->64 doubles grid to 1024 blocks -> 4 blocks/CU (128KB LDS,
// 2048 thr = exactly full), launch_bounds(512,8) pins it. (2) SLOT SHAVE -- drop
// the 2 f16 cvts: records split into two f32 streams {eo,y0,y1,y2} + {y3},
// rings depth 4. Per-step ~22 VALU slots (was 26).

typedef float    f32x2 __attribute__((ext_vector_type(2)));
typedef float    f32x4 __attribute__((ext_vector_type(4)));

#define NB 64
#define NS 2048
#define NH 256
#define CHUNKS 64
#define STEPS (NS / CHUNKS)   // 32
#define LOG2E 1.4426950408889634f
#define PAD 129

// tanh poly coefs (degree-7 odd, interpolation at x=.25,.5,.75,1)
#define TC1  0.9999015f
#define TC3 -0.3310469f
#define TC5  0.1204385f
#define TC7 -0.0276989f
// sigmoid(x)=0.5+x*q(x^2): q_k = c_k / 4^k
#define SC1  0.24997538f
#define SC3 -0.02069043f
#define SC5  0.00188185f
#define SC7 -0.00010820f

__global__ __launch_bounds__(256) void precompute_kernel(
    const float* __restrict__ X,     // [B][S][8]
    const float* __restrict__ emb,   // [128][124]
    const float* __restrict__ Wn,    // [4][7]
    const float* __restrict__ bn,    // [4]
    const float* __restrict__ Wc,    // [768][128]
    const float* __restrict__ bc,    // [768]
    float* __restrict__ T4f,         // out [128e][128p][4] {gz0,gz1,gf0,gf1} RAW
    float* __restrict__ Go,          // out [128e][256j]  o' (exp2-domain)
    f32x2* __restrict__ WzP,         // out [4][128] pair z-weights (raw)
    f32x2* __restrict__ WfP,         // out [4][128] pair f-weights (raw)
    float* __restrict__ Wgo4,        // out [4][256] (exp2-domain)
    f32x4* __restrict__ XpA,         // out [B*S+4] {eo, y0, y1, y2}
    float* __restrict__ XpB)         // out [B*S+4] y3
{
    const int tid = threadIdx.x;
    const int blk = blockIdx.x;

    if (blk < 256) {
        __shared__ float M[124 * PAD];      // emb^T: M[k*PAD + e] = emb[e][k]
        __shared__ float P[3][2][128];      // k-half partial sums
        {
            const int e = tid >> 1, half = tid & 1;
            const f32x4* er4 = (const f32x4*)(emb + (size_t)e * 124);
            #pragma unroll
            for (int i = 0; i < 16; ++i) {
                const int idx = half * 16 + i;
                if (idx < 31) {
                    const f32x4 v = er4[idx];
                    const int k0 = idx * 4;
                    M[(k0 + 0) * PAD + e] = v.x;
                    M[(k0 + 1) * PAD + e] = v.y;
                    M[(k0 + 2) * PAD + e] = v.z;
                    M[(k0 + 3) * PAD + e] = v.w;
                }
            }
        }
        __syncthreads();

        const int e = tid & 127;
        const int h = tid >> 7;          // k-half
        const int j = blk;               // channel
        const int k0 = h * 62;

        const float* __restrict__ wzr = Wc + (size_t)j * 128;
        const float* __restrict__ wfr = Wc + (size_t)(j + 256) * 128;
        const float* __restrict__ wor = Wc + (size_t)(j + 512) * 128;

        float az = 0.f, af = 0.f, ao = 0.f;
        #pragma unroll 31
        for (int i = 0; i < 62; ++i) {
            const int k = k0 + i;
            const float mv = M[k * PAD + e];
            az = fmaf(wzr[k], mv, az);
            af = fmaf(wfr[k], mv, af);
            ao = fmaf(wor[k], mv, ao);
        }
        P[0][h][e] = az; P[1][h][e] = af; P[2][h][e] = ao;
        __syncthreads();

        if (h == 0) {
            float sz = P[0][0][e] + P[0][1][e] + bc[j];
            float sf = P[1][0][e] + P[1][1][e] + bc[j + 256];
            float so = P[2][0][e] + P[2][1][e] + bc[j + 512];
            #pragma unroll
            for (int m = 0; m < 4; ++m) {
                const float bm = bn[m];
                sz = fmaf(wzr[124 + m], bm, sz);
                sf = fmaf(wfr[124 + m], bm, sf);
                so = fmaf(wor[124 + m], bm, so);
            }
            // pair layout: {gz(2p), gz(2p+1), gf(2p), gf(2p+1)} -- RAW pre-acts
            float* t4 = T4f + (((size_t)e * 128) + (j >> 1)) * 4;
            t4[(j & 1)]     = sz;
            t4[2 + (j & 1)] = sf;
            Go[(size_t)e * NH + j] = so * (-LOG2E);
        }
    } else if (blk == 256) {
        const int j = tid;
        #pragma unroll
        for (int m = 0; m < 4; ++m) {
            Wgo4[m * NH + j] = Wc[(size_t)(j + 512) * 128 + 124 + m] * (-LOG2E);
        }
        if (tid < 128) {
            const int p = tid, j0 = 2 * p, j1 = 2 * p + 1;
            #pragma unroll
            for (int m = 0; m < 4; ++m) {
                WzP[m * 128 + p] = (f32x2){
                    Wc[(size_t)j0 * 128 + 124 + m],
                    Wc[(size_t)j1 * 128 + 124 + m]};
                WfP[m * 128 + p] = (f32x2){
                    Wc[(size_t)(j0 + 256) * 128 + 124 + m],
                    Wc[(size_t)(j1 + 256) * 128 + 124 + m]};
            }
        }
        if (tid >= 128 && tid < 144) {
            ((float*)XpA)[(size_t)NB * NS * 4 + (tid - 128)] = 0.0f;  // 4 pad records
        }
        if (tid >= 144 && tid < 148) {
            XpB[(size_t)NB * NS + (tid - 144)] = 0.0f;
        }
    } else {
        // rank-4 record extraction: 128 blocks x 1024 records
        const f32x4* X4 = (const f32x4*)X;
        float wn[4][7];
        #pragma unroll
        for (int m = 0; m < 4; ++m)
            #pragma unroll
            for (int n = 0; n < 7; ++n) wn[m][n] = Wn[m * 7 + n];

        const int base = (blk - 257) * 1024 + tid;
        #pragma unroll
        for (int u = 0; u < 4; ++u) {
            const int idx = base + u * 256;
            const f32x4 xa = X4[(size_t)idx * 2];
            const f32x4 xb = X4[(size_t)idx * 2 + 1];
            const int eo = ((int)xa.x) << 8;    // byte offset of 256B LDS table row
            const float xs[7] = {xa.y, xa.z, xa.w, xb.x, xb.y, xb.z, xb.w};
            float y[4];
            #pragma unroll
            for (int m = 0; m < 4; ++m) {
                float s = 0.0f;
                #pragma unroll
                for (int n = 0; n < 7; ++n) s = fmaf(wn[m][n], xs[n], s);
                y[m] = s;
            }
            XpA[idx] = (f32x4){__int_as_float(eo), y[0], y[1], y[2]};
            XpB[idx] = y[3];
        }
    }
}

__global__ __launch_bounds__(512, 8) void scan_kernel(
    const f32x4* __restrict__ XpA,   // [B*S+4] {eo, y0, y1, y2}
    const float* __restrict__ XpB,   // [B*S+4] y3
    const f32x4* __restrict__ T4,    // [128e][128p] {gz0,gz1,gf0,gf1}
    const float* __restrict__ Go,    // [128][256]
    const f32x2* __restrict__ WzP,   // [4][128]
    const f32x2* __restrict__ WfP,   // [4][128]
    const float* __restrict__ Wgo4,  // [4][256]
    float* __restrict__ AB,          // [CHUNKS][B][2][256]
    float* __restrict__ Olast)       // [B][256]
{
    __shared__ f32x4 T[128 * 16];    // 32 KB: 16 channel-pairs x 128 events

    const int tid = threadIdx.x;
    const int pj = tid & 15;             // pair within block
    const int slice = tid >> 4;          // 0..31
    const int pbase = blockIdx.y * 16;

    #pragma unroll
    for (int i = tid; i < 2048; i += 512)
        T[i] = T4[(size_t)(i >> 4) * 128 + pbase + (i & 15)];
    __syncthreads();

    const int widx = (int)blockIdx.x * 32 + slice;
    const int b = widx >> 6;             // 64 chunks per batch
    const int c = widx & (CHUNKS - 1);
    const int p = pbase + pj;
    const int j0 = 2 * p;

    const f32x4* __restrict__ xa = XpA + ((size_t)b * NS + (size_t)c * STEPS);
    const float* __restrict__ xb = XpB + ((size_t)b * NS + (size_t)c * STEPS);
    const char*  __restrict__ Tb = (const char*)T;
    const int pj16 = pj * 16;

    f32x2 wz[4], wf[4];
    #pragma unroll
    for (int m = 0; m < 4; ++m) {
        wz[m] = WzP[m * 128 + p];
        wf[m] = WfP[m * 128 + p];
    }

    // rings: records depth 4 (3 ahead), table rows depth 2 (1 ahead)
    f32x4 rec[4];
    float y3r[4];
    f32x4 tv[2];
    rec[0] = xa[0];  y3r[0] = xb[0];
    rec[1] = xa[1];  y3r[1] = xb[1];
    rec[2] = xa[2];  y3r[2] = xb[2];
    tv[0] = *(const f32x4*)(Tb + (unsigned)__float_as_int(rec[0].x) + pj16);

    const f32x2 tc1 = (f32x2){TC1, TC1}, tc3 = (f32x2){TC3, TC3};
    const f32x2 tc5 = (f32x2){TC5, TC5}, tc7 = (f32x2){TC7, TC7};
    const f32x2 sc1 = (f32x2){SC1, SC1}, sc3 = (f32x2){SC3, SC3};
    const f32x2 sc5 = (f32x2){SC5, SC5}, sc7 = (f32x2){SC7, SC7};
    const f32x2 half2 = (f32x2){0.5f, 0.5f};

    f32x2 A = (f32x2){1.0f, 1.0f}, Bv = (f32x2){0.0f, 0.0f};

    #pragma unroll 4
    for (int t = 0; t < STEPS; ++t) {
        rec[(t + 3) & 3] = xa[t + 3];                               // vmcnt
        y3r[(t + 3) & 3] = xb[t + 3];                               // vmcnt
        tv[(t + 1) & 1] = *(const f32x4*)(
            Tb + (unsigned)__float_as_int(rec[(t + 1) & 3].x) + pj16);  // ds_read_b128

        const f32x4 ra = rec[t & 3];
        const float y3 = y3r[t & 3];
        const f32x4 g4 = tv[t & 1];

        f32x2 gz = (f32x2){g4.x, g4.y};
        f32x2 gf = (f32x2){g4.z, g4.w};
        gz = __builtin_elementwise_fma(wz[0], (f32x2){ra.y, ra.y}, gz);
        gf = __builtin_elementwise_fma(wf[0], (f32x2){ra.y, ra.y}, gf);
        gz = __builtin_elementwise_fma(wz[1], (f32x2){ra.z, ra.z}, gz);
        gf = __builtin_elementwise_fma(wf[1], (f32x2){ra.z, ra.z}, gf);
        gz = __builtin_elementwise_fma(wz[2], (f32x2){ra.w, ra.w}, gz);
        gf = __builtin_elementwise_fma(wf[2], (f32x2){ra.w, ra.w}, gf);
        gz = __builtin_elementwise_fma(wz[3], (f32x2){y3, y3}, gz);
        gf = __builtin_elementwise_fma(wf[3], (f32x2){y3, y3}, gf);

        // z = tanh(gz): degree-7 odd poly (no trans)
        const f32x2 uz = gz * gz;
        f32x2 pz = __builtin_elementwise_fma(tc7, uz, tc5);
        pz = __builtin_elementwise_fma(pz, uz, tc3);
        pz = __builtin_elementwise_fma(pz, uz, tc1);
        const f32x2 z = pz * gz;

        // f = sigmoid(gf) = 0.5 + gf * q(gf^2) (no trans)
        const f32x2 vf = gf * gf;
        f32x2 qf = __builtin_elementwise_fma(sc7, vf, sc5);
        qf = __builtin_elementwise_fma(qf, vf, sc3);
        qf = __builtin_elementwise_fma(qf, vf, sc1);
        const f32x2 f = __builtin_elementwise_fma(gf, qf, half2);

        A = A * f;
        const f32x2 s = Bv - z;
        Bv = __builtin_elementwise_fma(f, s, z);
    }

    *(f32x2*)(AB + (((size_t)c * NB + b) * 2 + 0) * NH + j0) = A;
    *(f32x2*)(AB + (((size_t)c * NB + b) * 2 + 1) * NH + j0) = Bv;

    if (c == CHUNKS - 1) {
        const f32x4 la = xa[STEPS - 1];
        const float ly3 = xb[STEPS - 1];
        const size_t eo = (size_t)(unsigned)__float_as_int(la.x);  // e<<8
        f32x2 go = *(const f32x2*)((const char*)Go + (eo << 2) + (size_t)j0 * 4);
        #pragma unroll
        for (int m = 0; m < 4; ++m) {
            const f32x2 wg = *(const f32x2*)(Wgo4 + m * NH + j0);
            const float ym = (m == 0) ? la.y : (m == 1) ? la.z : (m == 2) ? la.w : ly3;
            go = __builtin_elementwise_fma(wg, (f32x2){ym, ym}, go);
        }
        const f32x2 o = (f32x2){
            __builtin_amdgcn_rcpf(1.0f + __builtin_amdgcn_exp2f(go.x)),
            __builtin_amdgcn_rcpf(1.0f + __builtin_amdgcn_exp2f(go.y))};
        *(f32x2*)(Olast + b * NH + j0) = o;
    }
}

__global__ __launch_bounds__(256) void combine_kernel(
    const float* __restrict__ AB,     // [CHUNKS][B][2][256]
    const float* __restrict__ Olast,  // [B][256]
    const float* __restrict__ Wout,   // [1][256]
    const float* __restrict__ bout,   // [1]
    float* __restrict__ out)          // [B][1]
{
    const int b = blockIdx.x;
    const int j = threadIdx.x;

    float h = 0.0f;
    #pragma unroll 8
    for (int c = 0; c < CHUNKS; ++c) {
        const float A  = AB[(((size_t)c * NB + b) * 2 + 0) * NH + j];
        const float Bv = AB[(((size_t)c * NB + b) * 2 + 1) * NH + j];
        h = fmaf(A, h, Bv);
    }
    float v = Olast[b * NH + j] * h * Wout[j];

    #pragma unroll
    for (int off = 32; off > 0; off >>= 1) v += __shfl_down(v, off);
    __shared__ float red[4];
    if ((j & 63) == 0) red[j >> 6] = v;
    __syncthreads();
    if (j == 0) out[b] = red[0] + red[1] + red[2] + red[3] + bout[0];
}

extern "C" void kernel_launch(void* const* d_in, const int* in_sizes, int n_in,
                              void* d_out, int out_size, void* d_ws, size_t ws_size,
                              hipStream_t stream) {
    const float* X    = (const float*)d_in[0];
    const float* emb  = (const float*)d_in[1];
    const float* Wn   = (const float*)d_in[2];
    const float* bn   = (const float*)d_in[3];
    const float* Wc   = (const float*)d_in[4];
    const float* bc   = (const float*)d_in[5];
    const float* Wout = (const float*)d_in[6];
    const float* bout = (const float*)d_in[7];
    float* out = (float*)d_out;

    char* w = (char*)d_ws;
    float* T4f  = (float*)w;   w += (size_t)128 * 128 * 4 * sizeof(float);  // 256 KB
    float* Go   = (float*)w;   w += (size_t)128 * NH * sizeof(float);       // 128 KB
    f32x2* WzP  = (f32x2*)w;   w += 4 * 128 * sizeof(f32x2);
    f32x2* WfP  = (f32x2*)w;   w += 4 * 128 * sizeof(f32x2);
    float* Wgo4 = (float*)w;   w += 4 * NH * sizeof(float);
    float* AB   = (float*)w;   w += (size_t)CHUNKS * NB * 2 * NH * sizeof(float); // 8 MB
    float* Ol   = (float*)w;   w += NB * NH * sizeof(float);
    f32x4* XpA  = (f32x4*)w;   w += ((size_t)NB * NS + 4) * sizeof(f32x4);        // 2 MB + pad
    float* XpB  = (float*)w;   w += ((size_t)NB * NS + 4) * sizeof(float);        // 512 KB + pad

    precompute_kernel<<<385, 256, 0, stream>>>(X, emb, Wn, bn, Wc, bc,
                                               T4f, Go, WzP, WfP, Wgo4, XpA, XpB);
    dim3 gridS(128, 8);
    scan_kernel<<<gridS, 512, 0, stream>>>(XpA, XpB, (const f32x4*)T4f, Go,
                                           WzP, WfP, Wgo4, AB, Ol);
    combine_kernel<<<NB, 256, 0, stream>>>(AB, Ol, Wout, bout, out);
}

// Round 18
// 34.219 us; speedup vs baseline: 1.1436x; 1.1436x over previous
//
#include <hip/hip_runtime.h>

// QRNN fused kernel for MI355X.
// B=64, S=2048, VOCAB=128, HIDDEN=256, gates=768, emb=124, num=7.
//
// r18 = r16 geometry (best measured 32.9us; r17's occupancy experiment REGRESSED:
// CHUNKS=64 halved per-chunk amortization and doubled AB/combine for an issue
// rate already saturated at 4 waves/SIMD) + two issue-slot shaves:
//  (1) records as two f32 broadcast-VMEM streams {eo,y0,y1,y2} + {y3} -> the two
//      f16 cvts leave the hot loop (r17 validated this piece),
//  (2) sigmoid poly degree 7->5 (nodes 0.5/1.25/2.0, err<=1.5e-4 on |x|<=1).
// Scan remains VALU-issue-bound (~26 -> ~24 slots/step for 2 channels); tanh d7
// kept (dominates absmax). Ledger (r9 calibration): graph gaps are sub-us;
// scan ~28, precompute ~2.5, combine ~1.5.

typedef float    f32x2 __attribute__((ext_vector_type(2)));
typedef float    f32x4 __attribute__((ext_vector_type(4)));

#define NB 64
#define NS 2048
#define NH 256
#define CHUNKS 32
#define STEPS (NS / CHUNKS)   // 64
#define LOG2E 1.4426950408889634f
#define PAD 129

// tanh poly coefs (degree-7 odd, interpolation at x=.25,.5,.75,1)
#define TC1  0.9999015f
#define TC3 -0.3310469f
#define TC5  0.1204385f
#define TC7 -0.0276989f
// sigmoid(x)=0.5+x*q(x^2), degree-5 (nodes x=0.5,1.25,2.0)
#define SC1  0.2498024f
#define SC3 -0.0198500f
#define SC5  0.0012498f

__global__ __launch_bounds__(256) void precompute_kernel(
    const float* __restrict__ X,     // [B][S][8]
    const float* __restrict__ emb,   // [128][124]
    const float* __restrict__ Wn,    // [4][7]
    const float* __restrict__ bn,    // [4]
    const float* __restrict__ Wc,    // [768][128]
    const float* __restrict__ bc,    // [768]
    float* __restrict__ T4f,         // out [128e][128p][4] {gz0,gz1,gf0,gf1} RAW
    float* __restrict__ Go,          // out [128e][256j]  o' (exp2-domain)
    f32x2* __restrict__ WzP,         // out [4][128] pair z-weights (raw)
    f32x2* __restrict__ WfP,         // out [4][128] pair f-weights (raw)
    float* __restrict__ Wgo4,        // out [4][256] (exp2-domain)
    f32x4* __restrict__ XpA,         // out [B*S+4] {eo, y0, y1, y2}
    float* __restrict__ XpB)         // out [B*S+4] y3
{
    const int tid = threadIdx.x;
    const int blk = blockIdx.x;

    if (blk < 256) {
        __shared__ float M[124 * PAD];      // emb^T: M[k*PAD + e] = emb[e][k]
        __shared__ float P[3][2][128];      // k-half partial sums
        {
            const int e = tid >> 1, half = tid & 1;
            const f32x4* er4 = (const f32x4*)(emb + (size_t)e * 124);
            #pragma unroll
            for (int i = 0; i < 16; ++i) {
                const int idx = half * 16 + i;
                if (idx < 31) {
                    const f32x4 v = er4[idx];
                    const int k0 = idx * 4;
                    M[(k0 + 0) * PAD + e] = v.x;
                    M[(k0 + 1) * PAD + e] = v.y;
                    M[(k0 + 2) * PAD + e] = v.z;
                    M[(k0 + 3) * PAD + e] = v.w;
                }
            }
        }
        __syncthreads();

        const int e = tid & 127;
        const int h = tid >> 7;          // k-half
        const int j = blk;               // channel
        const int k0 = h * 62;

        const float* __restrict__ wzr = Wc + (size_t)j * 128;
        const float* __restrict__ wfr = Wc + (size_t)(j + 256) * 128;
        const float* __restrict__ wor = Wc + (size_t)(j + 512) * 128;

        float az = 0.f, af = 0.f, ao = 0.f;
        #pragma unroll 31
        for (int i = 0; i < 62; ++i) {
            const int k = k0 + i;
            const float mv = M[k * PAD + e];
            az = fmaf(wzr[k], mv, az);
            af = fmaf(wfr[k], mv, af);
            ao = fmaf(wor[k], mv, ao);
        }
        P[0][h][e] = az; P[1][h][e] = af; P[2][h][e] = ao;
        __syncthreads();

        if (h == 0) {
            float sz = P[0][0][e] + P[0][1][e] + bc[j];
            float sf = P[1][0][e] + P[1][1][e] + bc[j + 256];
            float so = P[2][0][e] + P[2][1][e] + bc[j + 512];
            #pragma unroll
            for (int m = 0; m < 4; ++m) {
                const float bm = bn[m];
                sz = fmaf(wzr[124 + m], bm, sz);
                sf = fmaf(wfr[124 + m], bm, sf);
                so = fmaf(wor[124 + m], bm, so);
            }
            // pair layout: {gz(2p), gz(2p+1), gf(2p), gf(2p+1)} -- RAW pre-acts
            float* t4 = T4f + (((size_t)e * 128) + (j >> 1)) * 4;
            t4[(j & 1)]     = sz;
            t4[2 + (j & 1)] = sf;
            Go[(size_t)e * NH + j] = so * (-LOG2E);
        }
    } else if (blk == 256) {
        const int j = tid;
        #pragma unroll
        for (int m = 0; m < 4; ++m) {
            Wgo4[m * NH + j] = Wc[(size_t)(j + 512) * 128 + 124 + m] * (-LOG2E);
        }
        if (tid < 128) {
            const int p = tid, j0 = 2 * p, j1 = 2 * p + 1;
            #pragma unroll
            for (int m = 0; m < 4; ++m) {
                WzP[m * 128 + p] = (f32x2){
                    Wc[(size_t)j0 * 128 + 124 + m],
                    Wc[(size_t)j1 * 128 + 124 + m]};
                WfP[m * 128 + p] = (f32x2){
                    Wc[(size_t)(j0 + 256) * 128 + 124 + m],
                    Wc[(size_t)(j1 + 256) * 128 + 124 + m]};
            }
        }
        if (tid >= 128 && tid < 144) {
            ((float*)XpA)[(size_t)NB * NS * 4 + (tid - 128)] = 0.0f;  // 4 pad records
        }
        if (tid >= 144 && tid < 148) {
            XpB[(size_t)NB * NS + (tid - 144)] = 0.0f;
        }
    } else {
        // rank-4 record extraction: 128 blocks x 1024 records
        const f32x4* X4 = (const f32x4*)X;
        float wn[4][7];
        #pragma unroll
        for (int m = 0; m < 4; ++m)
            #pragma unroll
            for (int n = 0; n < 7; ++n) wn[m][n] = Wn[m * 7 + n];

        const int base = (blk - 257) * 1024 + tid;
        #pragma unroll
        for (int u = 0; u < 4; ++u) {
            const int idx = base + u * 256;
            const f32x4 xa = X4[(size_t)idx * 2];
            const f32x4 xb = X4[(size_t)idx * 2 + 1];
            const int eo = ((int)xa.x) << 8;    // byte offset of 256B LDS table row
            const float xs[7] = {xa.y, xa.z, xa.w, xb.x, xb.y, xb.z, xb.w};
            float y[4];
            #pragma unroll
            for (int m = 0; m < 4; ++m) {
                float s = 0.0f;
                #pragma unroll
                for (int n = 0; n < 7; ++n) s = fmaf(wn[m][n], xs[n], s);
                y[m] = s;
            }
            XpA[idx] = (f32x4){__int_as_float(eo), y[0], y[1], y[2]};
            XpB[idx] = y[3];
        }
    }
}

__global__ __launch_bounds__(512) void scan_kernel(
    const f32x4* __restrict__ XpA,   // [B*S+4] {eo, y0, y1, y2}
    const float* __restrict__ XpB,   // [B*S+4] y3
    const f32x4* __restrict__ T4,    // [128e][128p] {gz0,gz1,gf0,gf1}
    const float* __restrict__ Go,    // [128][256]
    const f32x2* __restrict__ WzP,   // [4][128]
    const f32x2* __restrict__ WfP,   // [4][128]
    const float* __restrict__ Wgo4,  // [4][256]
    float* __restrict__ AB,          // [CHUNKS][B][2][256]
    float* __restrict__ Olast)       // [B][256]
{
    __shared__ f32x4 T[128 * 16];    // 32 KB: 16 channel-pairs x 128 events

    const int tid = threadIdx.x;
    const int pj = tid & 15;             // pair within block
    const int slice = tid >> 4;          // 0..31
    const int pbase = blockIdx.y * 16;

    #pragma unroll
    for (int i = tid; i < 2048; i += 512)
        T[i] = T4[(size_t)(i >> 4) * 128 + pbase + (i & 15)];
    __syncthreads();

    const int widx = (int)blockIdx.x * 32 + slice;
    const int b = widx >> 5;
    const int c = widx & (CHUNKS - 1);
    const int p = pbase + pj;
    const int j0 = 2 * p;

    const f32x4* __restrict__ xa = XpA + ((size_t)b * NS + (size_t)c * STEPS);
    const float* __restrict__ xb = XpB + ((size_t)b * NS + (size_t)c * STEPS);
    const char*  __restrict__ Tb = (const char*)T;
    const int pj16 = pj * 16;

    f32x2 wz[4], wf[4];
    #pragma unroll
    for (int m = 0; m < 4; ++m) {
        wz[m] = WzP[m * 128 + p];
        wf[m] = WfP[m * 128 + p];
    }

    // rings: records depth 4 (3 ahead), table rows depth 2 (1 ahead)
    f32x4 rec[4];
    float y3r[4];
    f32x4 tv[2];
    rec[0] = xa[0];  y3r[0] = xb[0];
    rec[1] = xa[1];  y3r[1] = xb[1];
    rec[2] = xa[2];  y3r[2] = xb[2];
    tv[0] = *(const f32x4*)(Tb + (unsigned)__float_as_int(rec[0].x) + pj16);

    const f32x2 tc1 = (f32x2){TC1, TC1}, tc3 = (f32x2){TC3, TC3};
    const f32x2 tc5 = (f32x2){TC5, TC5}, tc7 = (f32x2){TC7, TC7};
    const f32x2 sc1 = (f32x2){SC1, SC1}, sc3 = (f32x2){SC3, SC3};
    const f32x2 sc5 = (f32x2){SC5, SC5};
    const f32x2 half2 = (f32x2){0.5f, 0.5f};

    f32x2 A = (f32x2){1.0f, 1.0f}, Bv = (f32x2){0.0f, 0.0f};

    #pragma unroll 4
    for (int t = 0; t < STEPS; ++t) {
        rec[(t + 3) & 3] = xa[t + 3];                               // vmcnt
        y3r[(t + 3) & 3] = xb[t + 3];                               // vmcnt
        tv[(t + 1) & 1] = *(const f32x4*)(
            Tb + (unsigned)__float_as_int(rec[(t + 1) & 3].x) + pj16);  // ds_read_b128

        const f32x4 ra = rec[t & 3];
        const float y3 = y3r[t & 3];
        const f32x4 g4 = tv[t & 1];

        f32x2 gz = (f32x2){g4.x, g4.y};
        f32x2 gf = (f32x2){g4.z, g4.w};
        gz = __builtin_elementwise_fma(wz[0], (f32x2){ra.y, ra.y}, gz);
        gf = __builtin_elementwise_fma(wf[0], (f32x2){ra.y, ra.y}, gf);
        gz = __builtin_elementwise_fma(wz[1], (f32x2){ra.z, ra.z}, gz);
        gf = __builtin_elementwise_fma(wf[1], (f32x2){ra.z, ra.z}, gf);
        gz = __builtin_elementwise_fma(wz[2], (f32x2){ra.w, ra.w}, gz);
        gf = __builtin_elementwise_fma(wf[2], (f32x2){ra.w, ra.w}, gf);
        gz = __builtin_elementwise_fma(wz[3], (f32x2){y3, y3}, gz);
        gf = __builtin_elementwise_fma(wf[3], (f32x2){y3, y3}, gf);

        // z = tanh(gz): degree-7 odd poly (no trans)
        const f32x2 uz = gz * gz;
        f32x2 pz = __builtin_elementwise_fma(tc7, uz, tc5);
        pz = __builtin_elementwise_fma(pz, uz, tc3);
        pz = __builtin_elementwise_fma(pz, uz, tc1);
        const f32x2 z = pz * gz;

        // f = sigmoid(gf) = 0.5 + gf * q(gf^2), degree-5 (no trans)
        const f32x2 vf = gf * gf;
        f32x2 qf = __builtin_elementwise_fma(sc5, vf, sc3);
        qf = __builtin_elementwise_fma(qf, vf, sc1);
        const f32x2 f = __builtin_elementwise_fma(gf, qf, half2);

        A = A * f;
        const f32x2 s = Bv - z;
        Bv = __builtin_elementwise_fma(f, s, z);
    }

    *(f32x2*)(AB + (((size_t)c * NB + b) * 2 + 0) * NH + j0) = A;
    *(f32x2*)(AB + (((size_t)c * NB + b) * 2 + 1) * NH + j0) = Bv;

    if (c == CHUNKS - 1) {
        const f32x4 la = xa[STEPS - 1];
        const float ly3 = xb[STEPS - 1];
        const size_t eo = (size_t)(unsigned)__float_as_int(la.x);  // e<<8
        f32x2 go = *(const f32x2*)((const char*)Go + (eo << 2) + (size_t)j0 * 4);
        #pragma unroll
        for (int m = 0; m < 4; ++m) {
            const f32x2 wg = *(const f32x2*)(Wgo4 + m * NH + j0);
            const float ym = (m == 0) ? la.y : (m == 1) ? la.z : (m == 2) ? la.w : ly3;
            go = __builtin_elementwise_fma(wg, (f32x2){ym, ym}, go);
        }
        const f32x2 o = (f32x2){
            __builtin_amdgcn_rcpf(1.0f + __builtin_amdgcn_exp2f(go.x)),
            __builtin_amdgcn_rcpf(1.0f + __builtin_amdgcn_exp2f(go.y))};
        *(f32x2*)(Olast + b * NH + j0) = o;
    }
}

__global__ __launch_bounds__(256) void combine_kernel(
    const float* __restrict__ AB,     // [CHUNKS][B][2][256]
    const float* __restrict__ Olast,  // [B][256]
    const float* __restrict__ Wout,   // [1][256]
    const float* __restrict__ bout,   // [1]
    float* __restrict__ out)          // [B][1]
{
    const int b = blockIdx.x;
    const int j = threadIdx.x;

    float h = 0.0f;
    #pragma unroll 8
    for (int c = 0; c < CHUNKS; ++c) {
        const float A  = AB[(((size_t)c * NB + b) * 2 + 0) * NH + j];
        const float Bv = AB[(((size_t)c * NB + b) * 2 + 1) * NH + j];
        h = fmaf(A, h, Bv);
    }
    float v = Olast[b * NH + j] * h * Wout[j];

    #pragma unroll
    for (int off = 32; off > 0; off >>= 1) v += __shfl_down(v, off);
    __shared__ float red[4];
    if ((j & 63) == 0) red[j >> 6] = v;
    __syncthreads();
    if (j == 0) out[b] = red[0] + red[1] + red[2] + red[3] + bout[0];
}

extern "C" void kernel_launch(void* const* d_in, const int* in_sizes, int n_in,
                              void* d_out, int out_size, void* d_ws, size_t ws_size,
                              hipStream_t stream) {
    const float* X    = (const float*)d_in[0];
    const float* emb  = (const float*)d_in[1];
    const float* Wn   = (const float*)d_in[2];
    const float* bn   = (const float*)d_in[3];
    const float* Wc   = (const float*)d_in[4];
    const float* bc   = (const float*)d_in[5];
    const float* Wout = (const float*)d_in[6];
    const float* bout = (const float*)d_in[7];
    float* out = (float*)d_out;

    char* w = (char*)d_ws;
    float* T4f  = (float*)w;   w += (size_t)128 * 128 * 4 * sizeof(float);  // 256 KB
    float* Go   = (float*)w;   w += (size_t)128 * NH * sizeof(float);       // 128 KB
    f32x2* WzP  = (f32x2*)w;   w += 4 * 128 * sizeof(f32x2);
    f32x2* WfP  = (f32x2*)w;   w += 4 * 128 * sizeof(f32x2);
    float* Wgo4 = (float*)w;   w += 4 * NH * sizeof(float);
    float* AB   = (float*)w;   w += (size_t)CHUNKS * NB * 2 * NH * sizeof(float); // 4 MB
    float* Ol   = (float*)w;   w += NB * NH * sizeof(float);
    f32x4* XpA  = (f32x4*)w;   w += ((size_t)NB * NS + 4) * sizeof(f32x4);        // 2 MB + pad
    float* XpB  = (float*)w;   w += ((size_t)NB * NS + 4) * sizeof(float);        // 512 KB + pad

    precompute_kernel<<<385, 256, 0, stream>>>(X, emb, Wn, bn, Wc, bc,
                                               T4f, Go, WzP, WfP, Wgo4, XpA, XpB);
    dim3 gridS(64, 8);
    scan_kernel<<<gridS, 512, 0, stream>>>(XpA, XpB, (const f32x4*)T4f, Go,
                                           WzP, WfP, Wgo4, AB, Ol);
    combine_kernel<<<NB, 256, 0, stream>>>(AB, Ol, Wout, bout, out);
}